// Round 10
// baseline (331.282 us; speedup 1.0000x reference)
//
#include <hip/hip_runtime.h>

typedef __attribute__((ext_vector_type(8))) short bf16x8;
typedef __attribute__((ext_vector_type(4))) float f32x4;
typedef unsigned int       uint32;
typedef unsigned long long uint64;

#define DIM    64
#define KCB    1024
#define RPB    128        // rows per block
#define CHUNK  128        // entries staged per LDS chunk
#define NCHUNK 8
#define QCAP   2048

// dynamic LDS layout (bytes)
#define OFF_XS    0        // 128*64 f32  = 32768
#define OFF_EHI   32768    // 128*64 bf16 = 16384
#define OFF_CSQ   49152    // 1024 f32    = 4096
#define OFF_SLOT  53248    // 128 u64     = 1024
#define OFF_QUEUE 54272    // 2048 u32    = 8192
#define OFF_QCNT  62464    // 16
#define OFF_CODES 62480    // 128 i32     = 512
#define OFF_RED   62992    // 256 f32     = 1024
#define OFF_A     64016    // 128 f32     = 512
#define SMEM_BYTES 64528

__device__ __forceinline__ unsigned short f2bf(float f) {
    uint32 u = __float_as_uint(f);
    return (unsigned short)((u + 0x7fffu + ((u >> 16) & 1u)) >> 16);
}

// csq[k] = np.sum(cb*cb, axis=1) with numpy pairwise-8 order; zero loss acc.
__global__ void vq_prep(const float* __restrict__ cb, float* __restrict__ ws) {
    int k = blockIdx.x * blockDim.x + threadIdx.x;
    if (k < KCB) {
        const float* e = cb + (k << 6);
        {
            #pragma clang fp contract(off)
            float racc[8];
            #pragma unroll
            for (int j = 0; j < 8; ++j) racc[j] = e[j] * e[j];
            #pragma unroll
            for (int t = 1; t < 8; ++t) {
                #pragma unroll
                for (int j = 0; j < 8; ++j) racc[j] += e[8 * t + j] * e[8 * t + j];
            }
            ws[256 + k] = ((racc[0] + racc[1]) + (racc[2] + racc[3]))
                        + ((racc[4] + racc[5]) + (racc[6] + racc[7]));
        }
    }
    if (k == 0) ws[0] = 0.0f;
}

// Exact fp32 distance (bit-identical to the R1..R6 passing recipe) + lex-min
// update via packed u64 atomicMin: (d_bits<<32)|k. d>=0 -> fp bits order-
// monotone; equal d -> smaller k wins == numpy first-index tie-break.
__device__ __forceinline__ void exact_update(int row_l, int kg,
                                             const float* __restrict__ cb,
                                             const float* xs, const float* A_l,
                                             const float* csq_l, uint64* slot) {
    const float* ep = cb + ((size_t)kg << 6);
    const float* xr = xs + row_l * DIM;
    float m = 0.0f;
    #pragma unroll
    for (int c = 0; c < 16; ++c) {                 // j ascending, sequential chain
        float4 e4 = ((const float4*)ep)[c];
        float4 x4 = ((const float4*)xr)[c];
        m = __builtin_fmaf(x4.x, e4.x, m);
        m = __builtin_fmaf(x4.y, e4.y, m);
        m = __builtin_fmaf(x4.z, e4.z, m);
        m = __builtin_fmaf(x4.w, e4.w, m);
    }
    float d;
    {
        #pragma clang fp contract(off)
        d = (A_l[row_l] - 2.0f * m) + csq_l[kg];
    }
    uint64 v = (((uint64)__float_as_uint(d)) << 32) | (uint32)kg;
    atomicMin(slot + row_l, v);
}

// Single-pass hi-only-MFMA VQ with running-threshold exact rescue.
__global__ __launch_bounds__(256, 2) void vq_main(
        const float* __restrict__ in,
        const float* __restrict__ cb,
        const float* __restrict__ csq_g,    // = ws + 256
        float* __restrict__ codes_f,
        float* __restrict__ out,
        float* __restrict__ loss_acc)       // = ws + 0
{
    extern __shared__ char smem[];
    float*  xs    = (float*) (smem + OFF_XS);
    char*   ehi   = smem + OFF_EHI;
    float*  csq_l = (float*) (smem + OFF_CSQ);
    uint64* slot  = (uint64*)(smem + OFF_SLOT);
    uint32* queue = (uint32*)(smem + OFF_QUEUE);
    int*    qcnt  = (int*)   (smem + OFF_QCNT);
    int*    codes = (int*)   (smem + OFF_CODES);
    float*  red   = (float*) (smem + OFF_RED);
    float*  A_l   = (float*) (smem + OFF_A);

    const int tid  = threadIdx.x;
    const int lane = tid & 63;
    const int w    = __builtin_amdgcn_readfirstlane(tid >> 6);
    const int q    = lane >> 4;             // quad 0..3
    const int col  = lane & 15;
    const size_t rowBase = (size_t)blockIdx.x * RPB;

    // ---- stage x (linear row-major fp32) + init slot/qcnt ----
    {
        const uint4* gx = (const uint4*)(in + rowBase * DIM);
        uint4* lx = (uint4*)xs;
        #pragma unroll
        for (int i = 0; i < 8; ++i) lx[i * 256 + tid] = gx[i * 256 + tid];
    }
    if (tid < RPB) slot[tid] = ~0ull;
    if (tid == 0) *qcnt = 0;
    __syncthreads();

    // ---- A[row] exact (numpy pairwise-8) + stage csq ----
    if (tid < RPB) {
        const float* xr = xs + tid * DIM;
        {
            #pragma clang fp contract(off)
            float racc[8];
            #pragma unroll
            for (int j = 0; j < 8; ++j) racc[j] = xr[j] * xr[j];
            #pragma unroll
            for (int t = 1; t < 8; ++t) {
                #pragma unroll
                for (int j = 0; j < 8; ++j) racc[j] += xr[8*t+j] * xr[8*t+j];
            }
            A_l[tid] = ((racc[0] + racc[1]) + (racc[2] + racc[3]))
                     + ((racc[4] + racc[5]) + (racc[6] + racc[7]));
        }
    }
    #pragma unroll
    for (int i = 0; i < 4; ++i) csq_l[i * 256 + tid] = csq_g[i * 256 + tid];
    __syncthreads();

    // ---- A-frags (bf16 hi only), A_reg, margin ----
    // margin >= 2B, B <= 1.25e-4*sqrt(A)+3e-5 (hi-only drop terms, ||e||<=8/1024);
    // sqrt(A) <= (A+64)/16  ->  margin = 2.5e-5*A + 1.6e-3 has >=1.5x headroom.
    bf16x8 xhi[2][2];
    float  A_reg[2][4], marg[2][4], dmin[2][4], thr[2][4];
    #pragma unroll
    for (int rt = 0; rt < 2; ++rt) {
        const int row_l = (w * 2 + rt) * 16 + col;
        const float* xp = xs + row_l * DIM;
        #pragma unroll
        for (int kh = 0; kh < 2; ++kh) {
            const int base = kh * 32 + q * 8;
            #pragma unroll
            for (int j = 0; j < 8; ++j)
                xhi[rt][kh][j] = (short)f2bf(xp[base + j]);
        }
        #pragma unroll
        for (int r = 0; r < 4; ++r) {
            float a = A_l[(w * 2 + rt) * 16 + q * 4 + r];
            A_reg[rt][r] = a;
            marg[rt][r]  = __builtin_fmaf(a, 2.5e-5f, 1.6e-3f);
            dmin[rt][r]  = 3.402823466e38f;
            thr[rt][r]   = 3.402823466e38f;
        }
    }

    const int swz0 = q ^ (lane & 7);
    const int swz1 = (4 + q) ^ (lane & 7);

    // ---- stage chunk 0 ----
    {
        const int entry_l = tid >> 1, half = tid & 1;
        const float* ep = cb + ((size_t)entry_l) * DIM + half * 32;
        #pragma unroll
        for (int c2 = 0; c2 < 4; ++c2) {
            unsigned short hs[8];
            #pragma unroll
            for (int j = 0; j < 8; ++j) hs[j] = f2bf(ep[c2 * 8 + j]);
            const int swz = (half * 4 + c2) ^ (entry_l & 7);
            uint4 hv;
            hv.x = (uint32)hs[0] | ((uint32)hs[1] << 16);
            hv.y = (uint32)hs[2] | ((uint32)hs[3] << 16);
            hv.z = (uint32)hs[4] | ((uint32)hs[5] << 16);
            hv.w = (uint32)hs[6] | ((uint32)hs[7] << 16);
            *(uint4*)(ehi + entry_l * 128 + swz * 16) = hv;
        }
    }
    __syncthreads();

    // ---- seed: tile (c=0, et=0), min only (no pushes) ----
    {
        const int entry_l = col;
        const float cse = csq_l[entry_l];
        bf16x8 bh0 = *(const bf16x8*)(ehi + entry_l * 128 + swz0 * 16);
        bf16x8 bh1 = *(const bf16x8*)(ehi + entry_l * 128 + swz1 * 16);
        #pragma unroll
        for (int rt = 0; rt < 2; ++rt) {
            f32x4 acc = {0.f, 0.f, 0.f, 0.f};
            acc = __builtin_amdgcn_mfma_f32_16x16x32_bf16(xhi[rt][0], bh0, acc, 0, 0, 0);
            acc = __builtin_amdgcn_mfma_f32_16x16x32_bf16(xhi[rt][1], bh1, acc, 0, 0, 0);
            #pragma unroll
            for (int r = 0; r < 4; ++r) {
                float v = __builtin_fmaf(-2.0f, acc[r], A_reg[rt][r] + cse);
                v = fminf(v, __shfl_xor(v, 1));
                v = fminf(v, __shfl_xor(v, 2));
                v = fminf(v, __shfl_xor(v, 4));
                v = fminf(v, __shfl_xor(v, 8));
                dmin[rt][r] = v;
                thr[rt][r]  = v + marg[rt][r];
            }
        }
    }

    // ---- main single pass ----
    for (int c = 0; c < NCHUNK; ++c) {
        if (c > 0) {
            __syncthreads();
            const int entry_l = tid >> 1, half = tid & 1;
            const float* ep = cb + ((size_t)(c * CHUNK + entry_l)) * DIM + half * 32;
            #pragma unroll
            for (int c2 = 0; c2 < 4; ++c2) {
                unsigned short hs[8];
                #pragma unroll
                for (int j = 0; j < 8; ++j) hs[j] = f2bf(ep[c2 * 8 + j]);
                const int swz = (half * 4 + c2) ^ (entry_l & 7);
                uint4 hv;
                hv.x = (uint32)hs[0] | ((uint32)hs[1] << 16);
                hv.y = (uint32)hs[2] | ((uint32)hs[3] << 16);
                hv.z = (uint32)hs[4] | ((uint32)hs[5] << 16);
                hv.w = (uint32)hs[6] | ((uint32)hs[7] << 16);
                *(uint4*)(ehi + entry_l * 128 + swz * 16) = hv;
            }
            __syncthreads();
        }

        #pragma unroll 1
        for (int et = 0; et < 8; ++et) {
            const int entry_l = et * 16 + col;
            const int kg      = c * CHUNK + entry_l;
            const float cse   = csq_l[kg];
            bf16x8 bh0 = *(const bf16x8*)(ehi + entry_l * 128 + swz0 * 16);
            bf16x8 bh1 = *(const bf16x8*)(ehi + entry_l * 128 + swz1 * 16);

            float dh[2][4];
            #pragma unroll
            for (int rt = 0; rt < 2; ++rt) {
                f32x4 acc = {0.f, 0.f, 0.f, 0.f};
                acc = __builtin_amdgcn_mfma_f32_16x16x32_bf16(xhi[rt][0], bh0, acc, 0, 0, 0);
                acc = __builtin_amdgcn_mfma_f32_16x16x32_bf16(xhi[rt][1], bh1, acc, 0, 0, 0);
                #pragma unroll
                for (int r = 0; r < 4; ++r)
                    dh[rt][r] = __builtin_fmaf(-2.0f, acc[r], A_reg[rt][r] + cse);
            }

            // push candidates vs (lagged) running threshold — thr >= final thr
            // always, so every k with dh <= dmin_final + marg is captured.
            #pragma unroll
            for (int rt = 0; rt < 2; ++rt)
                #pragma unroll
                for (int r = 0; r < 4; ++r) {
                    if (dh[rt][r] <= thr[rt][r]) {
                        const int row_l = (w*2+rt)*16 + q*4 + r;
                        int idx = atomicAdd(qcnt, 1);
                        if (idx < QCAP) queue[idx] = ((uint32)row_l << 16) | (uint32)kg;
                        else exact_update(row_l, kg, cb, xs, A_l, csq_l, slot);
                    }
                }

            // tighten running min/threshold with this tile's row-min
            #pragma unroll
            for (int rt = 0; rt < 2; ++rt)
                #pragma unroll
                for (int r = 0; r < 4; ++r) {
                    float v = dh[rt][r];
                    v = fminf(v, __shfl_xor(v, 1));
                    v = fminf(v, __shfl_xor(v, 2));
                    v = fminf(v, __shfl_xor(v, 4));
                    v = fminf(v, __shfl_xor(v, 8));
                    if (v < dmin[rt][r]) {
                        dmin[rt][r] = v;
                        thr[rt][r]  = v + marg[rt][r];
                    }
                }
        }
    }

    // ---- drain queue: one exact fp32 chain per candidate ----
    __syncthreads();
    {
        int nq = *qcnt;
        if (nq > QCAP) nq = QCAP;
        for (int i = tid; i < nq; i += 256) {
            uint32 pk = queue[i];
            exact_update((int)(pk >> 16), (int)(pk & 0xffffu), cb, xs, A_l, csq_l, slot);
        }
    }
    __syncthreads();

    // ---- per-row result ----
    float db = 0.0f;
    if (tid < RPB) {
        uint64 s = slot[tid];
        int kbest = (int)(s & 0xffffffffu);
        db = __uint_as_float((uint32)(s >> 32));
        codes[tid] = kbest;
        codes_f[rowBase + tid] = (float)kbest;
    }
    red[tid] = db;          // tid>=128 contribute 0
    __syncthreads();

    // ---- straight-through write ----
    {
        float4* gout = (float4*)(out + rowBase * DIM);
        const float4* lx = (const float4*)xs;
        #pragma unroll
        for (int i = 0; i < 8; ++i) {
            int idx = i * 256 + tid;
            int row = idx >> 4, cj = idx & 15;
            int code = codes[row];
            float4 qv = *(const float4*)(cb + ((size_t)code << 6) + (cj << 2));
            float4 xv = lx[idx];
            float4 st;
            {
                #pragma clang fp contract(off)
                st.x = xv.x + (qv.x - xv.x);
                st.y = xv.y + (qv.y - xv.y);
                st.z = xv.z + (qv.z - xv.z);
                st.w = xv.w + (qv.w - xv.w);
            }
            gout[idx] = st;
        }
    }

    // ---- loss partial ----
    #pragma unroll
    for (int s = 128; s > 0; s >>= 1) {
        if (tid < s) red[tid] += red[tid + s];
        __syncthreads();
    }
    if (tid == 0) atomicAdd(loss_acc, red[0]);
}

__global__ void vq_final(const float* __restrict__ ws, float* __restrict__ loss_out) {
    loss_out[0] = 1.25f * ws[0] / 8388608.0f;   // 1.25 * mean((x-q)^2)
}

extern "C" void kernel_launch(void* const* d_in, const int* in_sizes, int n_in,
                              void* d_out, int out_size, void* d_ws, size_t ws_size,
                              hipStream_t stream) {
    const float* in = (const float*)d_in[0];   // (32,4096,64) fp32
    const float* cb = (const float*)d_in[1];   // (1024,64)    fp32
    float* out     = (float*)d_out;
    float* codes_f = out + 8388608;
    float* loss_p  = out + 8519680;
    float* ws      = (float*)d_ws;

    (void)hipFuncSetAttribute((const void*)vq_main,
                              hipFuncAttributeMaxDynamicSharedMemorySize, SMEM_BYTES);

    vq_prep <<<4,    256, 0,          stream>>>(cb, ws);
    vq_main <<<1024, 256, SMEM_BYTES, stream>>>(in, cb, ws + 256, codes_f, out, ws);
    vq_final<<<1,    1,   0,          stream>>>(ws, loss_p);
}